// Round 22
// baseline (249.147 us; speedup 1.0000x reference)
//
#include <hip/hip_runtime.h>

#define HW 128
#define NB 32
#define NL 68
#define NCHUNK 22

typedef __attribute__((ext_vector_type(8))) short bf8;
typedef __attribute__((ext_vector_type(8))) unsigned short us8;
typedef __attribute__((ext_vector_type(4))) unsigned short us4;
typedef __attribute__((ext_vector_type(4))) float f4;

__device__ __forceinline__ unsigned short f2bf(float f) {
    unsigned int u = __float_as_uint(f);
    u += 0x7fffu + ((u >> 16) & 1u);   // RNE
    return (unsigned short)(u >> 16);
}
__device__ __forceinline__ float bf2f(unsigned short v) {
    return __uint_as_float((unsigned int)v << 16);
}

// DPP wave shifts: shr1 -> lane i gets lane i-1 (0 into lane 0); shl1 -> lane i gets lane i+1 (0 into lane 63)
__device__ __forceinline__ float dpp_shr1(float x) {
    return __int_as_float(__builtin_amdgcn_update_dpp(0, __float_as_int(x), 0x138, 0xf, 0xf, true));
}
__device__ __forceinline__ float dpp_shl1(float x) {
    return __int_as_float(__builtin_amdgcn_update_dpp(0, __float_as_int(x), 0x130, 0xf, 0xf, true));
}
__device__ __forceinline__ float sget(float v) {   // force wave-uniform value into SGPR
    return __int_as_float(__builtin_amdgcn_readfirstlane(__float_as_int(v)));
}

// Wa[gl][o][k]: k = m*32 + kl, kl = tp*16 + ci (tp=tap&1 within pair), tap = 2m+tp
__global__ __launch_bounds__(256) void reorder_wa_kernel(const float* __restrict__ w,
                                                         unsigned short* __restrict__ wa) {
    int i = blockIdx.x * 256 + threadIdx.x;
    if (i >= 12 * 16 * 160) return;
    int k  = i % 160;
    int o  = (i / 160) % 16;
    int gl = i / 2560;
    int kl = k & 31, m = k >> 5;
    int tap = 2 * m + (kl >> 4);
    int ci  = kl & 15;
    float v = (tap < 9) ? w[((gl * 16 + o) * 16 + ci) * 9 + tap] : 0.f;
    wa[i] = f2bf(v);
}

// chunk -> landmark range (gate-aligned):
// jaw ch0-5, eyeA ch6-8, eyeB ch9-12, nose ch13-15, mouth ch16-21
__constant__ int CS_[NCHUNK] = {0,3,6,9,12,15, 17,20,23, 36,39,42,45, 27,30,33, 48,51,54,57,60,64};
__constant__ int CN_[NCHUNK] = {3,3,3,3,3,2,   3,3,4,    3,3,3,3,     3,3,3,    3,3,3,3,4, 4};

// Stage A (r18 structure): streaming partial-accumulator 5-layer depthwise towers.
// One WAVE = one (chunk, batch, 16-row band); lane owns 2 columns; halos via DPP;
// no LDS/barriers. Branch-free loads + DEPTH-5 register ring prefetch: 5 rows in
// flight x ~220 issue-cyc/row = ~1100 cyc cover > ~900 cyc HBM-miss latency (the
// depth-3 ring covered only ~660 -> VALUBusy 39%). +4 VGPR, far from spill.
__global__ __launch_bounds__(64, 3) void lm_stream_kernel(
    const float* __restrict__ lm, const float* __restrict__ wlm,
    const float* __restrict__ blm, unsigned short* __restrict__ gpart)
{
    const int lane  = threadIdx.x;
    const int chunk = blockIdx.x;
    const int b     = blockIdx.y;
    const int r0    = blockIdx.z << 4;   // band start row (uniform)
    const int c0    = lane << 1;
    const int ls    = CS_[chunk], lcnt = CN_[chunk];

    float ga[16][2];
    #pragma unroll
    for (int t = 0; t < 16; ++t) { ga[t][0] = 0.f; ga[t][1] = 0.f; }

    for (int li = 0; li < lcnt; ++li) {
        const int l = ls + li;
        const float* src = lm + (size_t)(b * NL + l) * (HW * HW) + c0;
        float wv_[5][9], bs[5];
        #pragma unroll
        for (int k = 0; k < 5; ++k) {
            #pragma unroll
            for (int t = 0; t < 9; ++t) wv_[k][t] = sget(wlm[(k * NL + l) * 9 + t]);
            bs[k] = sget(blm[k * NL + l]);
        }

        float a0[5][2], a1[5][2];
        #pragma unroll
        for (int k = 0; k < 5; ++k) {
            a0[k][0] = 0.f; a0[k][1] = 0.f;
            a1[k][0] = 0.f; a1[k][1] = 0.f;
        }

        // prime the 5-deep prefetch ring (clamped rows -> always-valid loads)
        float2 pre[5];
        #pragma unroll
        for (int j = 0; j < 5; ++j) {
            const int ir = r0 - 5 + j;
            const int irc = min(max(ir, 0), HW - 1);
            pre[j] = *(const float2*)(src + (size_t)irc * HW);
        }

        #pragma unroll
        for (int s = 0; s < 26; ++s) {
            const int ir = r0 - 5 + s;               // input row (uniform)
            const bool oki = (unsigned)ir < (unsigned)HW;
            const float2 v = pre[s % 5];             // s%5 static after unroll
            if (s + 5 < 26) {                        // refill slot with row s+5
                const int irn = ir + 5;
                const int irnc = min(max(irn, 0), HW - 1);
                pre[s % 5] = *(const float2*)(src + (size_t)irnc * HW);
            }
            float i0 = oki ? v.x : 0.f;              // cndmask, no branch
            float i1 = oki ? v.y : 0.f;
            #pragma unroll
            for (int k = 0; k < 5; ++k) {
                const float xl = dpp_shr1(i1);
                const float xr = dpp_shl1(i0);
                float o0 = a0[k][0], o1 = a0[k][1];
                o0 += wv_[k][6] * xl; o0 += wv_[k][7] * i0; o0 += wv_[k][8] * i1;
                o1 += wv_[k][6] * i0; o1 += wv_[k][7] * i1; o1 += wv_[k][8] * xr;
                float n0 = a1[k][0], n1 = a1[k][1];
                n0 += wv_[k][3] * xl; n0 += wv_[k][4] * i0; n0 += wv_[k][5] * i1;
                n1 += wv_[k][3] * i0; n1 += wv_[k][4] * i1; n1 += wv_[k][5] * xr;
                a0[k][0] = n0; a0[k][1] = n1;
                float m0 = bs[k], m1 = bs[k];
                m0 += wv_[k][0] * xl; m0 += wv_[k][1] * i0; m0 += wv_[k][2] * i1;
                m1 += wv_[k][0] * i0; m1 += wv_[k][1] * i1; m1 += wv_[k][2] * xr;
                a1[k][0] = m0; a1[k][1] = m1;
                const int orow = ir - 1 - k;
                const bool okr = (unsigned)orow < (unsigned)HW;  // SAME-padding zeroing
                i0 = okr ? o0 : 0.f;
                i1 = okr ? o1 : 0.f;
            }
            if (s >= 10) { ga[s - 10][0] += i0; ga[s - 10][1] += i1; }
        }
    }

    unsigned int* gp = (unsigned int*)(gpart + ((size_t)(chunk * NB + b) * HW + r0) * HW + c0);
    #pragma unroll
    for (int t = 0; t < 16; ++t)
        gp[(size_t)t * (HW / 2)] = (unsigned int)f2bf(ga[t][0]) | ((unsigned int)f2bf(ga[t][1]) << 16);
}

// One MFMA conv layer LDS(in)->LDS(out). SPLIT-HALF-PLANE layout: tile stored as two
// channel-half planes [h][pixel][8ch] (16 B/px/plane). Read address = plane(hb) +
// (base + delta[m])*8 shorts, delta loop-invariant -> one v_add per read, no swizzle.
template<int SIN, int PSIN, int SOUT, int OSTRIDE, int PSOUT, int OOFF, int HALO>
__device__ __forceinline__ void conv_layer_mfma(
    const unsigned short* __restrict__ inb, unsigned short* __restrict__ outb,
    const bf8* wf, f4 b4, int wave, int col, int g2, int hb,
    const int* drm, const int* dcm, int oy, int ox)
{
    constexpr int NPIX = SOUT * SOUT;
    constexpr int NT = (NPIX + 15) / 16;
    int d8[5];
    #pragma unroll
    for (int m = 0; m < 5; ++m) d8[m] = (drm[m] * SIN + dcm[m]) * 8;   // hoisted
    const unsigned short* inh = inb + hb * PSIN;
    unsigned short* outh = outb + (g2 >> 1) * PSOUT;
    for (int t = wave; t < NT; t += 4) {
        int pp = t * 16 + col;
        int ppc = pp < NPIX ? pp : NPIX - 1;
        int r = ppc / SOUT, c = ppc - r * SOUT;
        const unsigned short* pb = inh + (r * SIN + c) * 8;
        f4 acc = b4;
        #pragma unroll
        for (int m = 0; m < 5; ++m)
            acc = __builtin_amdgcn_mfma_f32_16x16x32_bf16(wf[m], *(const bf8*)(pb + d8[m]), acc, 0, 0, 0);
        if (pp < NPIX) {
            int gy = oy + r - HALO, gx = ox + c - HALO;
            bool valid = ((unsigned)gy < (unsigned)HW) & ((unsigned)gx < (unsigned)HW);
            us4 o4;
            o4.x = f2bf(valid ? acc[0] : 0.f);
            o4.y = f2bf(valid ? acc[1] : 0.f);
            o4.z = f2bf(valid ? acc[2] : 0.f);
            o4.w = f2bf(valid ? acc[3] : 0.f);
            int pout = (r + OOFF) * OSTRIDE + (c + OOFF);
            *(us4*)(outh + pout * 8 + (g2 & 1) * 4) = o4;
        }
    }
}

// Stage B (r18 known-good, bit-exact): stage once into TA+TA2 full shadow; per-branch
// restore = LDS->LDS copy; r12/r15 barrier structure; split-half-plane layout.
__global__ __launch_bounds__(256) void fea_mfma_kernel(
    const float* __restrict__ fea, const unsigned short* __restrict__ wa,
    const float* __restrict__ bfe, const unsigned short* __restrict__ gpart,
    float* __restrict__ out)
{
    // plane sizes (shorts): TA half-plane 484*8=3872, TB 400*8=3200
    __shared__ __align__(16) unsigned short TA[2 * 3872];   // 15488 B (working input)
    __shared__ __align__(16) unsigned short TB[2 * 3200];   // 12800 B
    __shared__ __align__(16) unsigned short TA2[2 * 3872];  // 15488 B (pristine copy)

    const int tid  = threadIdx.x;
    const int lane = tid & 63, wave = tid >> 6;
    const int col  = lane & 15, g2 = lane >> 4;
    const int tb   = g2 >> 1, hb = g2 & 1;
    const int b    = blockIdx.x >> 6;
    const int tile = blockIdx.x & 63;
    const int oy   = (tile >> 3) << 4;
    const int ox   = (tile & 7) << 4;

    int drm[5], dcm[5];
    #pragma unroll
    for (int m = 0; m < 5; ++m) {
        int tap = 2 * m + tb; if (tap > 8) tap = 8;
        int dr = (tap >= 6) ? 2 : ((tap >= 3) ? 1 : 0);
        drm[m] = dr; dcm[m] = tap - 3 * dr;
    }

    // ---- prefetch + sum gate planes into registers (latency hides under stage/L0/L1)
    // per-gate chunk-plane lists: eye=6..12, nose=13..15, jaw=0..5, mouth=16..21
    float gsum[4][4];
    #pragma unroll
    for (int g = 0; g < 4; ++g) {
        const int p0 = (g == 0) ? 6 : (g == 1) ? 13 : (g == 2) ? 0 : 16;
        const int np = (g == 0) ? 7 : (g == 1) ? 3 : 6;
        #pragma unroll
        for (int i = 0; i < 4; ++i) {
            const int r = wave * 4 + i;
            float s = 0.f;
            #pragma unroll
            for (int pp = 0; pp < 7; ++pp) {
                if (pp < np)
                    s += bf2f(gpart[(size_t)((p0 + pp) * NB + b) * (HW * HW)
                                    + (size_t)(oy + r) * HW + ox + col]);
            }
            gsum[g][i] = s;
        }
    }

    f4 oacc[4];
    #pragma unroll
    for (int i = 0; i < 4; ++i) oacc[i] = (f4)0.f;

    for (int g = 0; g < 4; ++g) {
        if (g == 0) {
            // stage features tile (halo 3) -> TA (and pristine copy TA2), split-half planes
            int p = tid;
            #pragma unroll
            for (int q = 0; q < 2; ++q, p += 256) {
                if (p < 484) {
                    int rr = p / 22, cc = p - rr * 22;
                    int gy = oy - 3 + rr, gx = ox - 3 + cc;
                    bool in = ((unsigned)gy < (unsigned)HW) & ((unsigned)gx < (unsigned)HW);
                    #pragma unroll
                    for (int h = 0; h < 2; ++h) {
                        us8 uv;
                        #pragma unroll
                        for (int j = 0; j < 8; ++j) {
                            float v = in ? fea[(((size_t)b * 16 + h * 8 + j) * HW + gy) * HW + gx] : 0.f;
                            uv[j] = f2bf(v);
                        }
                        const int off = h * 3872 + p * 8;
                        *(us8*)(TA + off)  = uv;
                        *(us8*)(TA2 + off) = uv;
                    }
                }
            }
        } else {
            // restore TA from TA2 (LDS->LDS)
            int p = tid;
            #pragma unroll
            for (int q = 0; q < 2; ++q, p += 256) {
                if (p < 484) {
                    #pragma unroll
                    for (int h = 0; h < 2; ++h) {
                        const int off = h * 3872 + p * 8;
                        *(us8*)(TA + off) = *(const us8*)(TA2 + off);
                    }
                }
            }
        }
        __syncthreads();

        const int gl = g * 3;
        bf8 wf[5];

        // layer 0: TA(22, ps 3872) -> TB(20x20, ps 3200)
        {
            const unsigned short* wp = wa + ((size_t)(gl + 0) * 16 + col) * 160 + g2 * 8;
            #pragma unroll
            for (int m = 0; m < 5; ++m) wf[m] = *(const bf8*)(wp + m * 32);
            f4 b4 = *(const f4*)(bfe + (gl + 0) * 16 + g2 * 4);
            conv_layer_mfma<22, 3872, 20, 20, 3200, 0, 2>(TA, TB, wf, b4, wave, col, g2, hb, drm, dcm, oy, ox);
        }
        __syncthreads();

        // layer 1: TB(20, ps 3200) -> TA at (2,2), 18x18 (stride 22, ps 3872)
        {
            const unsigned short* wp = wa + ((size_t)(gl + 1) * 16 + col) * 160 + g2 * 8;
            #pragma unroll
            for (int m = 0; m < 5; ++m) wf[m] = *(const bf8*)(wp + m * 32);
            f4 b4 = *(const f4*)(bfe + (gl + 1) * 16 + g2 * 4);
            conv_layer_mfma<20, 3200, 18, 22, 3872, 2, 1>(TB, TA, wf, b4, wave, col, g2, hb, drm, dcm, oy, ox);
        }
        __syncthreads();

        // layer 2: TA(2,2 offset, stride 22) -> registers, fused gate accumulate
        {
            const unsigned short* wp = wa + ((size_t)(gl + 2) * 16 + col) * 160 + g2 * 8;
            #pragma unroll
            for (int m = 0; m < 5; ++m) wf[m] = *(const bf8*)(wp + m * 32);
            f4 b4 = *(const f4*)(bfe + (gl + 2) * 16 + g2 * 4);
            int d8[5];
            #pragma unroll
            for (int m = 0; m < 5; ++m) d8[m] = (drm[m] * 22 + dcm[m]) * 8;
            const unsigned short* inh = TA + hb * 3872;
            #pragma unroll
            for (int i = 0; i < 4; ++i) {
                int r = wave * 4 + i;
                const unsigned short* pb = inh + ((r + 2) * 22 + (col + 2)) * 8;
                f4 acc = b4;
                #pragma unroll
                for (int m = 0; m < 5; ++m)
                    acc = __builtin_amdgcn_mfma_f32_16x16x32_bf16(wf[m], *(const bf8*)(pb + d8[m]), acc, 0, 0, 0);
                oacc[i] += gsum[g][i] * acc;
            }
        }
        __syncthreads();  // TA reads done before next branch's restore
    }

    #pragma unroll
    for (int i = 0; i < 4; ++i) {
        int gy = oy + wave * 4 + i;
        #pragma unroll
        for (int reg = 0; reg < 4; ++reg) {
            int och = g2 * 4 + reg;
            out[(((size_t)b * 16 + och) * HW + gy) * HW + ox + col] = oacc[i][reg];
        }
    }
}

extern "C" void kernel_launch(void* const* d_in, const int* in_sizes, int n_in,
                              void* d_out, int out_size, void* d_ws, size_t ws_size,
                              hipStream_t stream) {
    const float* lm  = (const float*)d_in[0];
    const float* fea = (const float*)d_in[1];
    const float* wlm = (const float*)d_in[2];
    const float* blm = (const float*)d_in[3];
    const float* wfe = (const float*)d_in[4];
    const float* bfe = (const float*)d_in[5];
    float* out = (float*)d_out;

    // ws: wa (64KB slot) | gpart 22 bf16 planes (23.1 MB)
    unsigned short* wa    = (unsigned short*)d_ws;
    unsigned short* gpart = (unsigned short*)((char*)d_ws + 65536);

    reorder_wa_kernel<<<120, 256, 0, stream>>>(wfe, wa);
    lm_stream_kernel<<<dim3(NCHUNK, NB, 8), 64, 0, stream>>>(lm, wlm, blm, gpart);
    fea_mfma_kernel<<<NB * 64, 256, 0, stream>>>(fea, wa, bfe, gpart, out);
}

// Round 23
// 201.138 us; speedup vs baseline: 1.2387x; 1.2387x over previous
//
#include <hip/hip_runtime.h>

#define HW 128
#define NB 32
#define NL 68
#define NCHUNK 22

typedef __attribute__((ext_vector_type(8))) short bf8;
typedef __attribute__((ext_vector_type(8))) unsigned short us8;
typedef __attribute__((ext_vector_type(4))) unsigned short us4;
typedef __attribute__((ext_vector_type(4))) float f4;

__device__ __forceinline__ unsigned short f2bf(float f) {
    unsigned int u = __float_as_uint(f);
    u += 0x7fffu + ((u >> 16) & 1u);   // RNE
    return (unsigned short)(u >> 16);
}
__device__ __forceinline__ float bf2f(unsigned short v) {
    return __uint_as_float((unsigned int)v << 16);
}

// DPP wave shifts: shr1 -> lane i gets lane i-1 (0 into lane 0); shl1 -> lane i gets lane i+1 (0 into lane 63)
__device__ __forceinline__ float dpp_shr1(float x) {
    return __int_as_float(__builtin_amdgcn_update_dpp(0, __float_as_int(x), 0x138, 0xf, 0xf, true));
}
__device__ __forceinline__ float dpp_shl1(float x) {
    return __int_as_float(__builtin_amdgcn_update_dpp(0, __float_as_int(x), 0x130, 0xf, 0xf, true));
}
__device__ __forceinline__ float sget(float v) {   // force wave-uniform value into SGPR
    return __int_as_float(__builtin_amdgcn_readfirstlane(__float_as_int(v)));
}

// Wa[gl][o][k]: k = m*32 + kl, kl = tp*16 + ci (tp=tap&1 within pair), tap = 2m+tp
__global__ __launch_bounds__(256) void reorder_wa_kernel(const float* __restrict__ w,
                                                         unsigned short* __restrict__ wa) {
    int i = blockIdx.x * 256 + threadIdx.x;
    if (i >= 12 * 16 * 160) return;
    int k  = i % 160;
    int o  = (i / 160) % 16;
    int gl = i / 2560;
    int kl = k & 31, m = k >> 5;
    int tap = 2 * m + (kl >> 4);
    int ci  = kl & 15;
    float v = (tap < 9) ? w[((gl * 16 + o) * 16 + ci) * 9 + tap] : 0.f;
    wa[i] = f2bf(v);
}

// chunk -> landmark range (gate-aligned):
// jaw ch0-5, eyeA ch6-8, eyeB ch9-12, nose ch13-15, mouth ch16-21
__constant__ int CS_[NCHUNK] = {0,3,6,9,12,15, 17,20,23, 36,39,42,45, 27,30,33, 48,51,54,57,60,64};
__constant__ int CN_[NCHUNK] = {3,3,3,3,3,2,   3,3,4,    3,3,3,3,     3,3,3,    3,3,3,3,4, 4};

// Stage A (r18/r21 known-good, FINAL): streaming partial-accumulator 5-layer depthwise
// towers. One WAVE = one (chunk, batch, 16-row band); lane owns 2 columns; halos via
// DPP; no LDS/barriers. Branch-free loads + DEPTH-3 ring prefetch — the maximum
// spill-free pipeline depth at (64,3): depth-5 (r22) and unbounded (r11) both spilled
// ~130-180 MB to scratch; 32-row bands (r20) likewise. Do not perturb.
__global__ __launch_bounds__(64, 3) void lm_stream_kernel(
    const float* __restrict__ lm, const float* __restrict__ wlm,
    const float* __restrict__ blm, unsigned short* __restrict__ gpart)
{
    const int lane  = threadIdx.x;
    const int chunk = blockIdx.x;
    const int b     = blockIdx.y;
    const int r0    = blockIdx.z << 4;   // band start row (uniform)
    const int c0    = lane << 1;
    const int ls    = CS_[chunk], lcnt = CN_[chunk];

    float ga[16][2];
    #pragma unroll
    for (int t = 0; t < 16; ++t) { ga[t][0] = 0.f; ga[t][1] = 0.f; }

    for (int li = 0; li < lcnt; ++li) {
        const int l = ls + li;
        const float* src = lm + (size_t)(b * NL + l) * (HW * HW) + c0;
        float wv_[5][9], bs[5];
        #pragma unroll
        for (int k = 0; k < 5; ++k) {
            #pragma unroll
            for (int t = 0; t < 9; ++t) wv_[k][t] = sget(wlm[(k * NL + l) * 9 + t]);
            bs[k] = sget(blm[k * NL + l]);
        }

        float a0[5][2], a1[5][2];
        #pragma unroll
        for (int k = 0; k < 5; ++k) {
            a0[k][0] = 0.f; a0[k][1] = 0.f;
            a1[k][0] = 0.f; a1[k][1] = 0.f;
        }

        // prime the 3-deep prefetch ring (clamped rows -> always-valid loads)
        float2 pre[3];
        #pragma unroll
        for (int j = 0; j < 3; ++j) {
            const int ir = r0 - 5 + j;
            const int irc = min(max(ir, 0), HW - 1);
            pre[j] = *(const float2*)(src + (size_t)irc * HW);
        }

        #pragma unroll
        for (int s = 0; s < 26; ++s) {
            const int ir = r0 - 5 + s;               // input row (uniform)
            const bool oki = (unsigned)ir < (unsigned)HW;
            const float2 v = pre[s % 3];             // s%3 static after unroll
            if (s + 3 < 26) {                        // refill slot with row s+3
                const int irn = ir + 3;
                const int irnc = min(max(irn, 0), HW - 1);
                pre[s % 3] = *(const float2*)(src + (size_t)irnc * HW);
            }
            float i0 = oki ? v.x : 0.f;              // cndmask, no branch
            float i1 = oki ? v.y : 0.f;
            #pragma unroll
            for (int k = 0; k < 5; ++k) {
                const float xl = dpp_shr1(i1);
                const float xr = dpp_shl1(i0);
                float o0 = a0[k][0], o1 = a0[k][1];
                o0 += wv_[k][6] * xl; o0 += wv_[k][7] * i0; o0 += wv_[k][8] * i1;
                o1 += wv_[k][6] * i0; o1 += wv_[k][7] * i1; o1 += wv_[k][8] * xr;
                float n0 = a1[k][0], n1 = a1[k][1];
                n0 += wv_[k][3] * xl; n0 += wv_[k][4] * i0; n0 += wv_[k][5] * i1;
                n1 += wv_[k][3] * i0; n1 += wv_[k][4] * i1; n1 += wv_[k][5] * xr;
                a0[k][0] = n0; a0[k][1] = n1;
                float m0 = bs[k], m1 = bs[k];
                m0 += wv_[k][0] * xl; m0 += wv_[k][1] * i0; m0 += wv_[k][2] * i1;
                m1 += wv_[k][0] * i0; m1 += wv_[k][1] * i1; m1 += wv_[k][2] * xr;
                a1[k][0] = m0; a1[k][1] = m1;
                const int orow = ir - 1 - k;
                const bool okr = (unsigned)orow < (unsigned)HW;  // SAME-padding zeroing
                i0 = okr ? o0 : 0.f;
                i1 = okr ? o1 : 0.f;
            }
            if (s >= 10) { ga[s - 10][0] += i0; ga[s - 10][1] += i1; }
        }
    }

    unsigned int* gp = (unsigned int*)(gpart + ((size_t)(chunk * NB + b) * HW + r0) * HW + c0);
    #pragma unroll
    for (int t = 0; t < 16; ++t)
        gp[(size_t)t * (HW / 2)] = (unsigned int)f2bf(ga[t][0]) | ((unsigned int)f2bf(ga[t][1]) << 16);
}

// One MFMA conv layer LDS(in)->LDS(out). SPLIT-HALF-PLANE layout: tile stored as two
// channel-half planes [h][pixel][8ch] (16 B/px/plane). Read address = plane(hb) +
// (base + delta[m])*8 shorts, delta loop-invariant -> one v_add per read, no swizzle.
template<int SIN, int PSIN, int SOUT, int OSTRIDE, int PSOUT, int OOFF, int HALO>
__device__ __forceinline__ void conv_layer_mfma(
    const unsigned short* __restrict__ inb, unsigned short* __restrict__ outb,
    const bf8* wf, f4 b4, int wave, int col, int g2, int hb,
    const int* drm, const int* dcm, int oy, int ox)
{
    constexpr int NPIX = SOUT * SOUT;
    constexpr int NT = (NPIX + 15) / 16;
    int d8[5];
    #pragma unroll
    for (int m = 0; m < 5; ++m) d8[m] = (drm[m] * SIN + dcm[m]) * 8;   // hoisted
    const unsigned short* inh = inb + hb * PSIN;
    unsigned short* outh = outb + (g2 >> 1) * PSOUT;
    for (int t = wave; t < NT; t += 4) {
        int pp = t * 16 + col;
        int ppc = pp < NPIX ? pp : NPIX - 1;
        int r = ppc / SOUT, c = ppc - r * SOUT;
        const unsigned short* pb = inh + (r * SIN + c) * 8;
        f4 acc = b4;
        #pragma unroll
        for (int m = 0; m < 5; ++m)
            acc = __builtin_amdgcn_mfma_f32_16x16x32_bf16(wf[m], *(const bf8*)(pb + d8[m]), acc, 0, 0, 0);
        if (pp < NPIX) {
            int gy = oy + r - HALO, gx = ox + c - HALO;
            bool valid = ((unsigned)gy < (unsigned)HW) & ((unsigned)gx < (unsigned)HW);
            us4 o4;
            o4.x = f2bf(valid ? acc[0] : 0.f);
            o4.y = f2bf(valid ? acc[1] : 0.f);
            o4.z = f2bf(valid ? acc[2] : 0.f);
            o4.w = f2bf(valid ? acc[3] : 0.f);
            int pout = (r + OOFF) * OSTRIDE + (c + OOFF);
            *(us4*)(outh + pout * 8 + (g2 & 1) * 4) = o4;
        }
    }
}

// Stage B (r18 known-good, FINAL): stage once into TA+TA2 full shadow; per-branch
// restore = LDS->LDS copy; r12/r15 barrier structure; split-half-plane layout.
__global__ __launch_bounds__(256) void fea_mfma_kernel(
    const float* __restrict__ fea, const unsigned short* __restrict__ wa,
    const float* __restrict__ bfe, const unsigned short* __restrict__ gpart,
    float* __restrict__ out)
{
    // plane sizes (shorts): TA half-plane 484*8=3872, TB 400*8=3200
    __shared__ __align__(16) unsigned short TA[2 * 3872];   // 15488 B (working input)
    __shared__ __align__(16) unsigned short TB[2 * 3200];   // 12800 B
    __shared__ __align__(16) unsigned short TA2[2 * 3872];  // 15488 B (pristine copy)

    const int tid  = threadIdx.x;
    const int lane = tid & 63, wave = tid >> 6;
    const int col  = lane & 15, g2 = lane >> 4;
    const int tb   = g2 >> 1, hb = g2 & 1;
    const int b    = blockIdx.x >> 6;
    const int tile = blockIdx.x & 63;
    const int oy   = (tile >> 3) << 4;
    const int ox   = (tile & 7) << 4;

    int drm[5], dcm[5];
    #pragma unroll
    for (int m = 0; m < 5; ++m) {
        int tap = 2 * m + tb; if (tap > 8) tap = 8;
        int dr = (tap >= 6) ? 2 : ((tap >= 3) ? 1 : 0);
        drm[m] = dr; dcm[m] = tap - 3 * dr;
    }

    // ---- prefetch + sum gate planes into registers (latency hides under stage/L0/L1)
    // per-gate chunk-plane lists: eye=6..12, nose=13..15, jaw=0..5, mouth=16..21
    float gsum[4][4];
    #pragma unroll
    for (int g = 0; g < 4; ++g) {
        const int p0 = (g == 0) ? 6 : (g == 1) ? 13 : (g == 2) ? 0 : 16;
        const int np = (g == 0) ? 7 : (g == 1) ? 3 : 6;
        #pragma unroll
        for (int i = 0; i < 4; ++i) {
            const int r = wave * 4 + i;
            float s = 0.f;
            #pragma unroll
            for (int pp = 0; pp < 7; ++pp) {
                if (pp < np)
                    s += bf2f(gpart[(size_t)((p0 + pp) * NB + b) * (HW * HW)
                                    + (size_t)(oy + r) * HW + ox + col]);
            }
            gsum[g][i] = s;
        }
    }

    f4 oacc[4];
    #pragma unroll
    for (int i = 0; i < 4; ++i) oacc[i] = (f4)0.f;

    for (int g = 0; g < 4; ++g) {
        if (g == 0) {
            // stage features tile (halo 3) -> TA (and pristine copy TA2), split-half planes
            int p = tid;
            #pragma unroll
            for (int q = 0; q < 2; ++q, p += 256) {
                if (p < 484) {
                    int rr = p / 22, cc = p - rr * 22;
                    int gy = oy - 3 + rr, gx = ox - 3 + cc;
                    bool in = ((unsigned)gy < (unsigned)HW) & ((unsigned)gx < (unsigned)HW);
                    #pragma unroll
                    for (int h = 0; h < 2; ++h) {
                        us8 uv;
                        #pragma unroll
                        for (int j = 0; j < 8; ++j) {
                            float v = in ? fea[(((size_t)b * 16 + h * 8 + j) * HW + gy) * HW + gx] : 0.f;
                            uv[j] = f2bf(v);
                        }
                        const int off = h * 3872 + p * 8;
                        *(us8*)(TA + off)  = uv;
                        *(us8*)(TA2 + off) = uv;
                    }
                }
            }
        } else {
            // restore TA from TA2 (LDS->LDS)
            int p = tid;
            #pragma unroll
            for (int q = 0; q < 2; ++q, p += 256) {
                if (p < 484) {
                    #pragma unroll
                    for (int h = 0; h < 2; ++h) {
                        const int off = h * 3872 + p * 8;
                        *(us8*)(TA + off) = *(const us8*)(TA2 + off);
                    }
                }
            }
        }
        __syncthreads();

        const int gl = g * 3;
        bf8 wf[5];

        // layer 0: TA(22, ps 3872) -> TB(20x20, ps 3200)
        {
            const unsigned short* wp = wa + ((size_t)(gl + 0) * 16 + col) * 160 + g2 * 8;
            #pragma unroll
            for (int m = 0; m < 5; ++m) wf[m] = *(const bf8*)(wp + m * 32);
            f4 b4 = *(const f4*)(bfe + (gl + 0) * 16 + g2 * 4);
            conv_layer_mfma<22, 3872, 20, 20, 3200, 0, 2>(TA, TB, wf, b4, wave, col, g2, hb, drm, dcm, oy, ox);
        }
        __syncthreads();

        // layer 1: TB(20, ps 3200) -> TA at (2,2), 18x18 (stride 22, ps 3872)
        {
            const unsigned short* wp = wa + ((size_t)(gl + 1) * 16 + col) * 160 + g2 * 8;
            #pragma unroll
            for (int m = 0; m < 5; ++m) wf[m] = *(const bf8*)(wp + m * 32);
            f4 b4 = *(const f4*)(bfe + (gl + 1) * 16 + g2 * 4);
            conv_layer_mfma<20, 3200, 18, 22, 3872, 2, 1>(TB, TA, wf, b4, wave, col, g2, hb, drm, dcm, oy, ox);
        }
        __syncthreads();

        // layer 2: TA(2,2 offset, stride 22) -> registers, fused gate accumulate
        {
            const unsigned short* wp = wa + ((size_t)(gl + 2) * 16 + col) * 160 + g2 * 8;
            #pragma unroll
            for (int m = 0; m < 5; ++m) wf[m] = *(const bf8*)(wp + m * 32);
            f4 b4 = *(const f4*)(bfe + (gl + 2) * 16 + g2 * 4);
            int d8[5];
            #pragma unroll
            for (int m = 0; m < 5; ++m) d8[m] = (drm[m] * 22 + dcm[m]) * 8;
            const unsigned short* inh = TA + hb * 3872;
            #pragma unroll
            for (int i = 0; i < 4; ++i) {
                int r = wave * 4 + i;
                const unsigned short* pb = inh + ((r + 2) * 22 + (col + 2)) * 8;
                f4 acc = b4;
                #pragma unroll
                for (int m = 0; m < 5; ++m)
                    acc = __builtin_amdgcn_mfma_f32_16x16x32_bf16(wf[m], *(const bf8*)(pb + d8[m]), acc, 0, 0, 0);
                oacc[i] += gsum[g][i] * acc;
            }
        }
        __syncthreads();  // TA reads done before next branch's restore
    }

    #pragma unroll
    for (int i = 0; i < 4; ++i) {
        int gy = oy + wave * 4 + i;
        #pragma unroll
        for (int reg = 0; reg < 4; ++reg) {
            int och = g2 * 4 + reg;
            out[(((size_t)b * 16 + och) * HW + gy) * HW + ox + col] = oacc[i][reg];
        }
    }
}

extern "C" void kernel_launch(void* const* d_in, const int* in_sizes, int n_in,
                              void* d_out, int out_size, void* d_ws, size_t ws_size,
                              hipStream_t stream) {
    const float* lm  = (const float*)d_in[0];
    const float* fea = (const float*)d_in[1];
    const float* wlm = (const float*)d_in[2];
    const float* blm = (const float*)d_in[3];
    const float* wfe = (const float*)d_in[4];
    const float* bfe = (const float*)d_in[5];
    float* out = (float*)d_out;

    // ws: wa (64KB slot) | gpart 22 bf16 planes (23.1 MB)
    unsigned short* wa    = (unsigned short*)d_ws;
    unsigned short* gpart = (unsigned short*)((char*)d_ws + 65536);

    reorder_wa_kernel<<<120, 256, 0, stream>>>(wfe, wa);
    lm_stream_kernel<<<dim3(NCHUNK, NB, 8), 64, 0, stream>>>(lm, wlm, blm, gpart);
    fea_mfma_kernel<<<NB * 64, 256, 0, stream>>>(fea, wa, bfe, gpart, out);
}

// Round 24
// 195.901 us; speedup vs baseline: 1.2718x; 1.0267x over previous
//
#include <hip/hip_runtime.h>

#define HW 128
#define NB 32
#define NL 68
#define NCHUNK 22

typedef __attribute__((ext_vector_type(8))) short bf8;
typedef __attribute__((ext_vector_type(8))) unsigned short us8;
typedef __attribute__((ext_vector_type(4))) unsigned short us4;
typedef __attribute__((ext_vector_type(4))) float f4;

__device__ __forceinline__ unsigned short f2bf(float f) {
    unsigned int u = __float_as_uint(f);
    u += 0x7fffu + ((u >> 16) & 1u);   // RNE
    return (unsigned short)(u >> 16);
}
__device__ __forceinline__ float bf2f(unsigned short v) {
    return __uint_as_float((unsigned int)v << 16);
}

// DPP wave shifts: shr1 -> lane i gets lane i-1 (0 into lane 0); shl1 -> lane i gets lane i+1 (0 into lane 63)
__device__ __forceinline__ float dpp_shr1(float x) {
    return __int_as_float(__builtin_amdgcn_update_dpp(0, __float_as_int(x), 0x138, 0xf, 0xf, true));
}
__device__ __forceinline__ float dpp_shl1(float x) {
    return __int_as_float(__builtin_amdgcn_update_dpp(0, __float_as_int(x), 0x130, 0xf, 0xf, true));
}
__device__ __forceinline__ float sget(float v) {   // force wave-uniform value into SGPR
    return __int_as_float(__builtin_amdgcn_readfirstlane(__float_as_int(v)));
}

// Wa[gl][o][k]: k = m*32 + kl, kl = tp*16 + ci (tp=tap&1 within pair), tap = 2m+tp
__global__ __launch_bounds__(256) void reorder_wa_kernel(const float* __restrict__ w,
                                                         unsigned short* __restrict__ wa) {
    int i = blockIdx.x * 256 + threadIdx.x;
    if (i >= 12 * 16 * 160) return;
    int k  = i % 160;
    int o  = (i / 160) % 16;
    int gl = i / 2560;
    int kl = k & 31, m = k >> 5;
    int tap = 2 * m + (kl >> 4);
    int ci  = kl & 15;
    float v = (tap < 9) ? w[((gl * 16 + o) * 16 + ci) * 9 + tap] : 0.f;
    wa[i] = f2bf(v);
}

// chunk -> landmark range (gate-aligned):
// jaw ch0-5, eyeA ch6-8, eyeB ch9-12, nose ch13-15, mouth ch16-21
__constant__ int CS_[NCHUNK] = {0,3,6,9,12,15, 17,20,23, 36,39,42,45, 27,30,33, 48,51,54,57,60,64};
__constant__ int CN_[NCHUNK] = {3,3,3,3,3,2,   3,3,4,    3,3,3,3,     3,3,3,    3,3,3,3,4, 4};

// Stage A (r18/r21 known-good, FINAL): streaming partial-accumulator 5-layer depthwise
// towers. One WAVE = one (chunk, batch, 16-row band); lane owns 2 columns; halos via
// DPP; no LDS/barriers. Branch-free loads + DEPTH-3 ring prefetch — the maximum
// spill-free pipeline depth at (64,3): depth-5 (r22) and unbounded (r11) both spilled
// ~130-180 MB to scratch; 32-row bands (r20) likewise. Do not perturb.
__global__ __launch_bounds__(64, 3) void lm_stream_kernel(
    const float* __restrict__ lm, const float* __restrict__ wlm,
    const float* __restrict__ blm, unsigned short* __restrict__ gpart)
{
    const int lane  = threadIdx.x;
    const int chunk = blockIdx.x;
    const int b     = blockIdx.y;
    const int r0    = blockIdx.z << 4;   // band start row (uniform)
    const int c0    = lane << 1;
    const int ls    = CS_[chunk], lcnt = CN_[chunk];

    float ga[16][2];
    #pragma unroll
    for (int t = 0; t < 16; ++t) { ga[t][0] = 0.f; ga[t][1] = 0.f; }

    for (int li = 0; li < lcnt; ++li) {
        const int l = ls + li;
        const float* src = lm + (size_t)(b * NL + l) * (HW * HW) + c0;
        float wv_[5][9], bs[5];
        #pragma unroll
        for (int k = 0; k < 5; ++k) {
            #pragma unroll
            for (int t = 0; t < 9; ++t) wv_[k][t] = sget(wlm[(k * NL + l) * 9 + t]);
            bs[k] = sget(blm[k * NL + l]);
        }

        float a0[5][2], a1[5][2];
        #pragma unroll
        for (int k = 0; k < 5; ++k) {
            a0[k][0] = 0.f; a0[k][1] = 0.f;
            a1[k][0] = 0.f; a1[k][1] = 0.f;
        }

        // prime the 3-deep prefetch ring (clamped rows -> always-valid loads)
        float2 pre[3];
        #pragma unroll
        for (int j = 0; j < 3; ++j) {
            const int ir = r0 - 5 + j;
            const int irc = min(max(ir, 0), HW - 1);
            pre[j] = *(const float2*)(src + (size_t)irc * HW);
        }

        #pragma unroll
        for (int s = 0; s < 26; ++s) {
            const int ir = r0 - 5 + s;               // input row (uniform)
            const bool oki = (unsigned)ir < (unsigned)HW;
            const float2 v = pre[s % 3];             // s%3 static after unroll
            if (s + 3 < 26) {                        // refill slot with row s+3
                const int irn = ir + 3;
                const int irnc = min(max(irn, 0), HW - 1);
                pre[s % 3] = *(const float2*)(src + (size_t)irnc * HW);
            }
            float i0 = oki ? v.x : 0.f;              // cndmask, no branch
            float i1 = oki ? v.y : 0.f;
            #pragma unroll
            for (int k = 0; k < 5; ++k) {
                const float xl = dpp_shr1(i1);
                const float xr = dpp_shl1(i0);
                float o0 = a0[k][0], o1 = a0[k][1];
                o0 += wv_[k][6] * xl; o0 += wv_[k][7] * i0; o0 += wv_[k][8] * i1;
                o1 += wv_[k][6] * i0; o1 += wv_[k][7] * i1; o1 += wv_[k][8] * xr;
                float n0 = a1[k][0], n1 = a1[k][1];
                n0 += wv_[k][3] * xl; n0 += wv_[k][4] * i0; n0 += wv_[k][5] * i1;
                n1 += wv_[k][3] * i0; n1 += wv_[k][4] * i1; n1 += wv_[k][5] * xr;
                a0[k][0] = n0; a0[k][1] = n1;
                float m0 = bs[k], m1 = bs[k];
                m0 += wv_[k][0] * xl; m0 += wv_[k][1] * i0; m0 += wv_[k][2] * i1;
                m1 += wv_[k][0] * i0; m1 += wv_[k][1] * i1; m1 += wv_[k][2] * xr;
                a1[k][0] = m0; a1[k][1] = m1;
                const int orow = ir - 1 - k;
                const bool okr = (unsigned)orow < (unsigned)HW;  // SAME-padding zeroing
                i0 = okr ? o0 : 0.f;
                i1 = okr ? o1 : 0.f;
            }
            if (s >= 10) { ga[s - 10][0] += i0; ga[s - 10][1] += i1; }
        }
    }

    unsigned int* gp = (unsigned int*)(gpart + ((size_t)(chunk * NB + b) * HW + r0) * HW + c0);
    #pragma unroll
    for (int t = 0; t < 16; ++t)
        gp[(size_t)t * (HW / 2)] = (unsigned int)f2bf(ga[t][0]) | ((unsigned int)f2bf(ga[t][1]) << 16);
}

// One MFMA conv layer LDS(in)->LDS(out). SPLIT-HALF-PLANE layout: tile stored as two
// channel-half planes [h][pixel][8ch] (16 B/px/plane). Read address = plane(hb) +
// (base + delta[m])*8 shorts, delta loop-invariant -> one v_add per read, no swizzle.
template<int SIN, int PSIN, int SOUT, int OSTRIDE, int PSOUT, int OOFF, int HALO>
__device__ __forceinline__ void conv_layer_mfma(
    const unsigned short* __restrict__ inb, unsigned short* __restrict__ outb,
    const bf8* wf, f4 b4, int wave, int col, int g2, int hb,
    const int* drm, const int* dcm, int oy, int ox)
{
    constexpr int NPIX = SOUT * SOUT;
    constexpr int NT = (NPIX + 15) / 16;
    int d8[5];
    #pragma unroll
    for (int m = 0; m < 5; ++m) d8[m] = (drm[m] * SIN + dcm[m]) * 8;   // hoisted
    const unsigned short* inh = inb + hb * PSIN;
    unsigned short* outh = outb + (g2 >> 1) * PSOUT;
    for (int t = wave; t < NT; t += 4) {
        int pp = t * 16 + col;
        int ppc = pp < NPIX ? pp : NPIX - 1;
        int r = ppc / SOUT, c = ppc - r * SOUT;
        const unsigned short* pb = inh + (r * SIN + c) * 8;
        f4 acc = b4;
        #pragma unroll
        for (int m = 0; m < 5; ++m)
            acc = __builtin_amdgcn_mfma_f32_16x16x32_bf16(wf[m], *(const bf8*)(pb + d8[m]), acc, 0, 0, 0);
        if (pp < NPIX) {
            int gy = oy + r - HALO, gx = ox + c - HALO;
            bool valid = ((unsigned)gy < (unsigned)HW) & ((unsigned)gx < (unsigned)HW);
            us4 o4;
            o4.x = f2bf(valid ? acc[0] : 0.f);
            o4.y = f2bf(valid ? acc[1] : 0.f);
            o4.z = f2bf(valid ? acc[2] : 0.f);
            o4.w = f2bf(valid ? acc[3] : 0.f);
            int pout = (r + OOFF) * OSTRIDE + (c + OOFF);
            *(us4*)(outh + pout * 8 + (g2 & 1) * 4) = o4;
        }
    }
}

// Stage B: RESTORE-FREE variant of the r18 structure. Pristine tile lives in TA2
// (staged once, NEVER written again); L0 reads TA2 directly each branch; TA is pure
// scratch that L1 fills (interior (2,2)..(19,19), stride 22 — the bit-identical
// write path of the passing r18 kernel) and L2 consumes. The per-branch TA2->TA
// restore and TA's staging writes are deleted. Barrier structure kept identical
// (4/branch, some now redundant but harmless) — one variable changed vs r23.
__global__ __launch_bounds__(256) void fea_mfma_kernel(
    const float* __restrict__ fea, const unsigned short* __restrict__ wa,
    const float* __restrict__ bfe, const unsigned short* __restrict__ gpart,
    float* __restrict__ out)
{
    // plane sizes (shorts): TA/TA2 half-plane 484*8=3872, TB 400*8=3200
    __shared__ __align__(16) unsigned short TA[2 * 3872];   // 15488 B (L1 scratch)
    __shared__ __align__(16) unsigned short TB[2 * 3200];   // 12800 B
    __shared__ __align__(16) unsigned short TA2[2 * 3872];  // 15488 B (pristine input)

    const int tid  = threadIdx.x;
    const int lane = tid & 63, wave = tid >> 6;
    const int col  = lane & 15, g2 = lane >> 4;
    const int tb   = g2 >> 1, hb = g2 & 1;
    const int b    = blockIdx.x >> 6;
    const int tile = blockIdx.x & 63;
    const int oy   = (tile >> 3) << 4;
    const int ox   = (tile & 7) << 4;

    int drm[5], dcm[5];
    #pragma unroll
    for (int m = 0; m < 5; ++m) {
        int tap = 2 * m + tb; if (tap > 8) tap = 8;
        int dr = (tap >= 6) ? 2 : ((tap >= 3) ? 1 : 0);
        drm[m] = dr; dcm[m] = tap - 3 * dr;
    }

    // ---- prefetch + sum gate planes into registers (latency hides under stage/L0/L1)
    // per-gate chunk-plane lists: eye=6..12, nose=13..15, jaw=0..5, mouth=16..21
    float gsum[4][4];
    #pragma unroll
    for (int g = 0; g < 4; ++g) {
        const int p0 = (g == 0) ? 6 : (g == 1) ? 13 : (g == 2) ? 0 : 16;
        const int np = (g == 0) ? 7 : (g == 1) ? 3 : 6;
        #pragma unroll
        for (int i = 0; i < 4; ++i) {
            const int r = wave * 4 + i;
            float s = 0.f;
            #pragma unroll
            for (int pp = 0; pp < 7; ++pp) {
                if (pp < np)
                    s += bf2f(gpart[(size_t)((p0 + pp) * NB + b) * (HW * HW)
                                    + (size_t)(oy + r) * HW + ox + col]);
            }
            gsum[g][i] = s;
        }
    }

    f4 oacc[4];
    #pragma unroll
    for (int i = 0; i < 4; ++i) oacc[i] = (f4)0.f;

    for (int g = 0; g < 4; ++g) {
        if (g == 0) {
            // stage features tile (halo 3) -> TA2 ONLY (pristine; L0 reads it directly)
            int p = tid;
            #pragma unroll
            for (int q = 0; q < 2; ++q, p += 256) {
                if (p < 484) {
                    int rr = p / 22, cc = p - rr * 22;
                    int gy = oy - 3 + rr, gx = ox - 3 + cc;
                    bool in = ((unsigned)gy < (unsigned)HW) & ((unsigned)gx < (unsigned)HW);
                    #pragma unroll
                    for (int h = 0; h < 2; ++h) {
                        us8 uv;
                        #pragma unroll
                        for (int j = 0; j < 8; ++j) {
                            float v = in ? fea[(((size_t)b * 16 + h * 8 + j) * HW + gy) * HW + gx] : 0.f;
                            uv[j] = f2bf(v);
                        }
                        *(us8*)(TA2 + h * 3872 + p * 8) = uv;
                    }
                }
            }
        }
        // no restore: TA2 is never corrupted; TA is scratch refilled by L1 each branch
        __syncthreads();

        const int gl = g * 3;
        bf8 wf[5];

        // layer 0: TA2(22, ps 3872) -> TB(20x20, ps 3200)   [reads pristine buffer]
        {
            const unsigned short* wp = wa + ((size_t)(gl + 0) * 16 + col) * 160 + g2 * 8;
            #pragma unroll
            for (int m = 0; m < 5; ++m) wf[m] = *(const bf8*)(wp + m * 32);
            f4 b4 = *(const f4*)(bfe + (gl + 0) * 16 + g2 * 4);
            conv_layer_mfma<22, 3872, 20, 20, 3200, 0, 2>(TA2, TB, wf, b4, wave, col, g2, hb, drm, dcm, oy, ox);
        }
        __syncthreads();

        // layer 1: TB(20, ps 3200) -> TA at (2,2), 18x18 (stride 22, ps 3872)
        {
            const unsigned short* wp = wa + ((size_t)(gl + 1) * 16 + col) * 160 + g2 * 8;
            #pragma unroll
            for (int m = 0; m < 5; ++m) wf[m] = *(const bf8*)(wp + m * 32);
            f4 b4 = *(const f4*)(bfe + (gl + 1) * 16 + g2 * 4);
            conv_layer_mfma<20, 3200, 18, 22, 3872, 2, 1>(TB, TA, wf, b4, wave, col, g2, hb, drm, dcm, oy, ox);
        }
        __syncthreads();

        // layer 2: TA(2,2 offset, stride 22) -> registers, fused gate accumulate
        // (reads rows/cols 2..19 — exactly the region L1 wrote)
        {
            const unsigned short* wp = wa + ((size_t)(gl + 2) * 16 + col) * 160 + g2 * 8;
            #pragma unroll
            for (int m = 0; m < 5; ++m) wf[m] = *(const bf8*)(wp + m * 32);
            f4 b4 = *(const f4*)(bfe + (gl + 2) * 16 + g2 * 4);
            int d8[5];
            #pragma unroll
            for (int m = 0; m < 5; ++m) d8[m] = (drm[m] * 22 + dcm[m]) * 8;
            const unsigned short* inh = TA + hb * 3872;
            #pragma unroll
            for (int i = 0; i < 4; ++i) {
                int r = wave * 4 + i;
                const unsigned short* pb = inh + ((r + 2) * 22 + (col + 2)) * 8;
                f4 acc = b4;
                #pragma unroll
                for (int m = 0; m < 5; ++m)
                    acc = __builtin_amdgcn_mfma_f32_16x16x32_bf16(wf[m], *(const bf8*)(pb + d8[m]), acc, 0, 0, 0);
                oacc[i] += gsum[g][i] * acc;
            }
        }
        __syncthreads();  // kept (protects TB/TA phase boundaries conservatively)
    }

    #pragma unroll
    for (int i = 0; i < 4; ++i) {
        int gy = oy + wave * 4 + i;
        #pragma unroll
        for (int reg = 0; reg < 4; ++reg) {
            int och = g2 * 4 + reg;
            out[(((size_t)b * 16 + och) * HW + gy) * HW + ox + col] = oacc[i][reg];
        }
    }
}

extern "C" void kernel_launch(void* const* d_in, const int* in_sizes, int n_in,
                              void* d_out, int out_size, void* d_ws, size_t ws_size,
                              hipStream_t stream) {
    const float* lm  = (const float*)d_in[0];
    const float* fea = (const float*)d_in[1];
    const float* wlm = (const float*)d_in[2];
    const float* blm = (const float*)d_in[3];
    const float* wfe = (const float*)d_in[4];
    const float* bfe = (const float*)d_in[5];
    float* out = (float*)d_out;

    // ws: wa (64KB slot) | gpart 22 bf16 planes (23.1 MB)
    unsigned short* wa    = (unsigned short*)d_ws;
    unsigned short* gpart = (unsigned short*)((char*)d_ws + 65536);

    reorder_wa_kernel<<<120, 256, 0, stream>>>(wfe, wa);
    lm_stream_kernel<<<dim3(NCHUNK, NB, 8), 64, 0, stream>>>(lm, wlm, blm, gpart);
    fea_mfma_kernel<<<NB * 64, 256, 0, stream>>>(fea, wa, bfe, gpart, out);
}